// Round 5
// baseline (231.764 us; speedup 1.0000x reference)
//
#include <hip/hip_runtime.h>

// ---------------------------------------------------------------------------
// TinySelfAttention: B=4 S=2048 D=1024 H=16 HD=64, fp32 in/out.
// R12: k_attn half-tile software pipeline (k_prep/k_qkv byte-identical R11).
//  - Two static register sets A/B (a-accumulators + V fragments) alternate
//    over half-tiles; each half's softmax+PV executes AFTER the next half's
//    QK MFMA cluster: exp reads stale (ready) accumulators and issues on the
//    VALU pipe while the QK chain drains the MFMA pipe -> removes the
//    per-half MFMA-latency stall (the ~20% both-pipes-idle in R11 PMC).
//  - SMPV execution order over halves unchanged -> denominator and ov
//    accumulation bitwise identical to R11.
//  - V fragments of the pending half carried in VGPRs across the iteration
//    barrier (LDS double-buffer semantics untouched).
// Retained: mask-tile-as-C, permlane32_swap transpose, setprio clusters,
// fixed-shift softmax, XOR-swizzled glds staging, LDS-transpose epilogues,
// k_qkv ring-3 + 2-phase split with counted vmcnt(6).
// ---------------------------------------------------------------------------

typedef __bf16 bf16_t;
typedef __bf16 bf16x2 __attribute__((ext_vector_type(2)));
typedef __bf16 bf16x4 __attribute__((ext_vector_type(4)));
typedef __bf16 bf16x8 __attribute__((ext_vector_type(8)));
typedef float floatx16 __attribute__((ext_vector_type(16)));
typedef float floatx4 __attribute__((ext_vector_type(4)));
typedef float floatx2 __attribute__((ext_vector_type(2)));

__device__ __forceinline__ void glds16(const void* g, void* l) {
  __builtin_amdgcn_global_load_lds(
      (const __attribute__((address_space(1))) void*)g,
      (__attribute__((address_space(3))) void*)l, 16, 0, 0);
}

__device__ __forceinline__ float exp2_fast(float x) {
  return __builtin_amdgcn_exp2f(x);
}

__device__ __forceinline__ unsigned pk2(float a, float b) {
  union { bf16x2 v; unsigned u; } cv;
  cv.v[0] = (bf16_t)a; cv.v[1] = (bf16_t)b;
  return cv.u;
}

// lane-half swap: a' = [a_lo | b_lo], b' = [a_hi | b_hi]
__device__ __forceinline__ void plane32(unsigned& a, unsigned& b) {
  asm("v_permlane32_swap_b32 %0, %1" : "+v"(a), "+v"(b));
}

// --------------------- prep: X->bf16  and  W->Wt bf16 ----------------------
__global__ __launch_bounds__(256) void k_prep(const float* __restrict__ X,
                                              bf16_t* __restrict__ Xb,
                                              const float* __restrict__ Wq,
                                              const float* __restrict__ Wk,
                                              const float* __restrict__ Wv,
                                              bf16_t* __restrict__ Wt) {
  int bid = blockIdx.x;
  if (bid < 8192) {  // X convert: 1024 f32 per block
    int i = (bid * 256 + threadIdx.x) * 4;
    float4 v = *(const float4*)(X + i);
    bf16x4 o;
    o[0] = (bf16_t)v.x; o[1] = (bf16_t)v.y; o[2] = (bf16_t)v.z; o[3] = (bf16_t)v.w;
    *(bf16x4*)(Xb + i) = o;
  } else {  // W transpose: 3 x 1024 blocks of 32x32 tiles
    int t = bid - 8192;
    int z = t >> 10, r2 = t & 1023;
    int bx = r2 & 31, by = r2 >> 5;
    const float* W = (z == 0) ? Wq : ((z == 1) ? Wk : Wv);
    bf16_t* dst = Wt + (size_t)z * 1048576;
    __shared__ float tt[32][33];
    int tx = threadIdx.x & 31, ty = threadIdx.x >> 5;
#pragma unroll
    for (int r = 0; r < 4; r++) {
      int k = by * 32 + ty + r * 8;
      tt[ty + r * 8][tx] = W[k * 1024 + bx * 32 + tx];
    }
    __syncthreads();
#pragma unroll
    for (int r = 0; r < 4; r++) {
      int n = bx * 32 + ty + r * 8;
      dst[(size_t)n * 1024 + by * 32 + tx] = (bf16_t)tt[tx][ty + r * 8];
    }
  }
}

// ----------------------------- fused QKV GEMM ------------------------------
// 512 threads / 8 waves; tile 128(M) x 256(N); waves 0-3 = N-half 0, 4-7 =
// N-half 1. Ring-3 LDS slots of 48KB (A 16KB + B 32KB). Per K-tile: 2 phases
// of 16 MFMA each, staging for t+2 interleaved per-phase, vmcnt(6) boundary.
#define QKV_STAGE_A(kt, slot)                                 \
  do {                                                        \
    bf16_t* sA_ = lds + (slot) * 24576;                       \
    bf16_t* sB_ = sA_ + 8192;                                 \
    glds16(gA0 + (kt) * 64, sA_ + dA0);                       \
    glds16(gA1 + (kt) * 64, sA_ + dA1);                       \
    glds16(gB0 + (kt) * 64, sB_ + dB0);                       \
  } while (0)
#define QKV_STAGE_B(kt, slot)                                 \
  do {                                                        \
    bf16_t* sA_ = lds + (slot) * 24576;                       \
    bf16_t* sB_ = sA_ + 8192;                                 \
    glds16(gB1 + (kt) * 64, sB_ + dB1);                       \
    glds16(gB2 + (kt) * 64, sB_ + dB2);                       \
    glds16(gB3 + (kt) * 64, sB_ + dB3);                       \
  } while (0)

__global__ __launch_bounds__(512, 2) void k_qkv(
    const bf16_t* __restrict__ Xb, const bf16_t* __restrict__ Wt,
    const float* __restrict__ bq, const float* __restrict__ bk,
    const float* __restrict__ bv, bf16_t* __restrict__ Qb,
    bf16_t* __restrict__ Kb, bf16_t* __restrict__ Vt) {
  extern __shared__ bf16_t lds[];  // 147456 B = 3 slots x 24576 elems
  int tid = threadIdx.x, wv = tid >> 6, lane = tid & 63;
  int wvv = wv & 3, half = wv >> 2;
  int quad = lane >> 4, l16 = lane & 15;
  int wm = wvv >> 1, wn = wvv & 1;

  int id = blockIdx.x;  // 768 = 8(XCD) x 12(bn) x 8(pm)
  int x = id & 7, w = id >> 3;
  int bn = w >> 3, pm = w & 7;
  int bm = x * 8 + pm;
  size_t m0 = (size_t)bm * 128, n0 = (size_t)bn * 256;
  int wsel = bn >> 2;  // 0=Q 1=K 2=V (uniform per block)

  const bf16_t* Ab = Xb + m0 * 1024;
  const bf16_t* Bb = Wt + n0 * 1024;

  // staging pointers: A = 2 chunks/thread (16KB), B = 4 chunks/thread (32KB)
  const bf16_t *gA0, *gA1, *gB0, *gB1, *gB2, *gB3;
  int dA0, dA1, dB0, dB1, dB2, dB3;
  {
    int r8 = lane >> 3, l8 = lane & 7;
    int jA0 = wv * 2, jA1 = wv * 2 + 1;
    int rA0 = jA0 * 8 + r8, rA1 = jA1 * 8 + r8;
    gA0 = Ab + (size_t)rA0 * 1024 + ((l8 ^ (rA0 & 7)) * 8);
    gA1 = Ab + (size_t)rA1 * 1024 + ((l8 ^ (rA1 & 7)) * 8);
    dA0 = jA0 * 512; dA1 = jA1 * 512;
    int jB = wv * 4;
    int rB0 = (jB + 0) * 8 + r8, rB1 = (jB + 1) * 8 + r8;
    int rB2 = (jB + 2) * 8 + r8, rB3 = (jB + 3) * 8 + r8;
    gB0 = Bb + (size_t)rB0 * 1024 + ((l8 ^ (rB0 & 7)) * 8);
    gB1 = Bb + (size_t)rB1 * 1024 + ((l8 ^ (rB1 & 7)) * 8);
    gB2 = Bb + (size_t)rB2 * 1024 + ((l8 ^ (rB2 & 7)) * 8);
    gB3 = Bb + (size_t)rB3 * 1024 + ((l8 ^ (rB3 & 7)) * 8);
    dB0 = (jB + 0) * 512; dB1 = (jB + 1) * 512;
    dB2 = (jB + 2) * 512; dB3 = (jB + 3) * 512;
  }

  // fragment read offsets (within a 128x64 tile, 8x16B-slot XOR swizzle)
  int ofsA[2][4], ofsB[2][4];
#pragma unroll
  for (int s = 0; s < 2; s++)
#pragma unroll
    for (int rt = 0; rt < 4; rt++) {
      int rowa = wm * 64 + rt * 16 + l16;
      ofsA[s][rt] = rowa * 64 + (((4 * s + quad) ^ (rowa & 7)) * 8);
      int rowb = wn * 64 + rt * 16 + l16;
      ofsB[s][rt] = rowb * 64 + (((4 * s + quad) ^ (rowb & 7)) * 8);
    }

  floatx4 acc[4][4];
#pragma unroll
  for (int a = 0; a < 4; a++)
#pragma unroll
    for (int b = 0; b < 4; b++)
#pragma unroll
      for (int r = 0; r < 4; r++) acc[a][b][r] = 0.f;

  // prologue: stage tiles 0 and 1 (12 loads/thread in flight)
  QKV_STAGE_A(0, 0); QKV_STAGE_B(0, 0);
  QKV_STAGE_A(1, 1); QKV_STAGE_B(1, 1);

#pragma unroll
  for (int t = 0; t < 16; ++t) {
    // boundary: all waves done reading slot (t-1)%3 (= (t+2)%3, WAR-safe)
    asm volatile("" ::: "memory");
    __builtin_amdgcn_s_barrier();
    // retire tile t's 6 loads; leave t+1's 6 in flight (t+2 not yet issued)
    if (t < 15) asm volatile("s_waitcnt vmcnt(6)" ::: "memory");
    else        asm volatile("s_waitcnt vmcnt(0)" ::: "memory");
    __builtin_amdgcn_sched_barrier(0);
    __builtin_amdgcn_s_barrier();  // tile t visible to all waves
    asm volatile("" ::: "memory");

    const bf16_t* sA = lds + (t % 3) * 24576;
    const bf16_t* sBh = sA + 8192 + half * 8192;
    // V blocks compute the transposed GEMM (operand swap; both tiles 128x64)
    const bf16_t* fA = (wsel == 2) ? sBh : sA;
    const bf16_t* fB = (wsel == 2) ? sA : sBh;

    // ---- phase A: k-slice s=0 ----
    if (t + 2 < 16) QKV_STAGE_A(t + 2, (t + 2) % 3);
    {
      bf16x8 av[4], bw[4];
#pragma unroll
      for (int rt = 0; rt < 4; rt++) {
        av[rt] = *(const bf16x8*)(fA + ofsA[0][rt]);
        bw[rt] = *(const bf16x8*)(fB + ofsB[0][rt]);
      }
      __builtin_amdgcn_s_setprio(1);
#pragma unroll
      for (int rt = 0; rt < 4; rt++)
#pragma unroll
        for (int ct = 0; ct < 4; ct++)
          acc[rt][ct] = __builtin_amdgcn_mfma_f32_16x16x32_bf16(av[rt], bw[ct],
                                                               acc[rt][ct], 0, 0, 0);
      __builtin_amdgcn_s_setprio(0);
    }
    asm volatile("" ::: "memory");
    __builtin_amdgcn_s_barrier();  // phase stagger
    asm volatile("" ::: "memory");

    // ---- phase B: k-slice s=1 ----
    if (t + 2 < 16) QKV_STAGE_B(t + 2, (t + 2) % 3);
    {
      bf16x8 av[4], bw[4];
#pragma unroll
      for (int rt = 0; rt < 4; rt++) {
        av[rt] = *(const bf16x8*)(fA + ofsA[1][rt]);
        bw[rt] = *(const bf16x8*)(fB + ofsB[1][rt]);
      }
      __builtin_amdgcn_s_setprio(1);
#pragma unroll
      for (int rt = 0; rt < 4; rt++)
#pragma unroll
        for (int ct = 0; ct < 4; ct++)
          acc[rt][ct] = __builtin_amdgcn_mfma_f32_16x16x32_bf16(av[rt], bw[ct],
                                                               acc[rt][ct], 0, 0, 0);
      __builtin_amdgcn_s_setprio(0);
    }
  }

  // ---- epilogue: LDS transpose -> fully coalesced bf16x8 stores ----
  __syncthreads();  // safe reuse of ring LDS as two 32KB C tiles (one/half)
  bf16_t* shC = lds + half * 16384;  // [128][128] bf16 per N-half
  int s0 = (int)(m0 & 2047), bb = (int)(m0 >> 11);
  int n0h = (int)(n0 & 1023) + half * 128;
  int hbase = n0h >> 6;
  int th = tid & 255;

  if (wsel == 2) {
    // acc is C^T: nl = wm*64+rt*16+quad*4+r, ml = wn*64+ct*16+l16. LDS [nl][ml].
#pragma unroll
    for (int rt = 0; rt < 4; rt++) {
#pragma unroll
      for (int r = 0; r < 4; r++) {
        int nl = wm * 64 + rt * 16 + quad * 4 + r;
        float bi = bv[n0h + nl];
#pragma unroll
        for (int ct = 0; ct < 4; ct++) {
          int ml = wn * 64 + ct * 16 + l16;
          shC[nl * 128 + ml] = (bf16_t)(acc[rt][ct][r] + bi);
        }
      }
    }
    __syncthreads();
    // Vt[(bb*16+hh)*131072 + dd*2048 + (s0+ml)]; 256B spans per row nl
#pragma unroll
    for (int p = 0; p < 8; p++) {
      int c = p * 256 + th;  // 2048 chunks of 16B per half
      int nl = c >> 4, mo = (c & 15) * 8;
      bf16x8 vv = *(const bf16x8*)(shC + nl * 128 + mo);
      int hh = hbase + (nl >> 6), dd = nl & 63;
      *(bf16x8*)(Vt + (size_t)(bb * 16 + hh) * 131072 + (size_t)dd * 2048 + s0 + mo) = vv;
    }
  } else {
    const float* bias = (wsel == 0) ? bq : bk;
    // acc is C: ml = wm*64+rt*16+quad*4+r, nl = wn*64+ct*16+l16. LDS [ml][nl].
#pragma unroll
    for (int ct = 0; ct < 4; ct++) {
      int nl = wn * 64 + ct * 16 + l16;
      float bi = bias[n0h + nl];
#pragma unroll
      for (int rt = 0; rt < 4; rt++) {
#pragma unroll
        for (int r = 0; r < 4; r++) {
          int ml = wm * 64 + rt * 16 + quad * 4 + r;
          float v = acc[rt][ct][r] + bi;
          shC[ml * 128 + nl] =
              (wsel == 0) ? (bf16_t)(v * 0.18033688011117f) : (bf16_t)v;
        }
      }
    }
    __syncthreads();
    bf16_t* outp = (wsel == 0) ? Qb : Kb;
    // per half: two heads h in {0,1}, each 128 rows x 64 dd contiguous
#pragma unroll
    for (int p = 0; p < 8; p++) {
      int c = p * 256 + th;  // 2048 chunks of 16B per half
      int h = c >> 10, c1 = c & 1023;
      int ml = c1 >> 3, ko = (c1 & 7) * 8;
      bf16x8 vv = *(const bf16x8*)(shC + ml * 128 + h * 64 + ko);
      *(bf16x8*)(outp + (size_t)(bb * 16 + hbase + h) * 131072 +
                 (size_t)(s0 + ml) * 64 + ko) = vv;
    }
  }
}

// ------------------------------ attention ----------------------------------
// 256 threads (4 waves), grid 512 = 2 blocks/CU. Block = (bh, 256-q tile);
// wave = 64 q (two 32-q MFMA n-tiles sharing every kf/vf LDS read). 32 iters
// of 64 keys, double-buffered glds. Half-tile software pipeline: SMPV of the
// previous half runs after the current half's QK cluster (sets A/B alternate
// statically). Mask tile as initial C; fixed-shift softmax p = exp2(s + m12).
// LDS 40960B: staging 32K | mask 8K.

// QK for half TT of the current tile -> accumulators A0R/A1R; V fragments
// for the pending SMPV saved in VFA/VFB (registers, survive the barrier).
#define QKHALF(TT, A0R, A1R, VFA, VFB)                                        \
  do {                                                                        \
    bf16x8 kf_[4];                                                            \
    _Pragma("unroll")                                                         \
    for (int s_ = 0; s_ < 4; s_++)                                            \
      kf_[s_] = *(const bf16x8*)(bK + off[TT][s_]);                           \
    _Pragma("unroll")                                                         \
    for (int t2_ = 0; t2_ < 2; t2_++) {                                       \
      (VFA)[t2_] = *(const bf16x8*)(bV + off[t2_][(TT) * 2]);                 \
      (VFB)[t2_] = *(const bf16x8*)(bV + off[t2_][(TT) * 2 + 1]);             \
    }                                                                         \
    __builtin_amdgcn_s_setprio(1);                                            \
    floatx16 mt_ = __builtin_amdgcn_mfma_f32_32x32x16_bf16(kfe[TT].v, qfe.v,  \
                                                           zed, 0, 0, 0);     \
    (A0R) = __builtin_amdgcn_mfma_f32_32x32x16_bf16(kf_[0], qf0[0], mt_, 0, 0, 0); \
    (A1R) = __builtin_amdgcn_mfma_f32_32x32x16_bf16(kf_[0], qf1[0], mt_, 0, 0, 0); \
    _Pragma("unroll")                                                         \
    for (int s_ = 1; s_ < 4; s_++) {                                          \
      (A0R) = __builtin_amdgcn_mfma_f32_32x32x16_bf16(kf_[s_], qf0[s_], (A0R), 0, 0, 0); \
      (A1R) = __builtin_amdgcn_mfma_f32_32x32x16_bf16(kf_[s_], qf1[s_], (A1R), 0, 0, 0); \
    }                                                                         \
    __builtin_amdgcn_s_setprio(0);                                            \
  } while (0)

// softmax + PV for a completed half (accumulators + saved V fragments).
#define SMPV(A0R, A1R, VFA, VFB)                                              \
  do {                                                                        \
    _Pragma("unroll")                                                         \
    for (int sl_ = 0; sl_ < 2; sl_++) {                                       \
      int base_ = sl_ * 8;                                                    \
      float e0 = exp2_fast((A0R)[base_ + 0]);                                 \
      float e1 = exp2_fast((A0R)[base_ + 1]);                                 \
      float e2 = exp2_fast((A0R)[base_ + 2]);                                 \
      float e3 = exp2_fast((A0R)[base_ + 3]);                                 \
      float e4 = exp2_fast((A0R)[base_ + 4]);                                 \
      float e5 = exp2_fast((A0R)[base_ + 5]);                                 \
      float e6 = exp2_fast((A0R)[base_ + 6]);                                 \
      float e7 = exp2_fast((A0R)[base_ + 7]);                                 \
      floatx2 u0_, u1_;                                                       \
      u0_[0] = e0 + e4; u0_[1] = e1 + e5; pA0 += u0_;                         \
      u1_[0] = e2 + e6; u1_[1] = e3 + e7; pA1 += u1_;                         \
      unsigned A0_ = pk2(e0, e1), B0_ = pk2(e2, e3);                          \
      unsigned C0_ = pk2(e4, e5), D0_ = pk2(e6, e7);                          \
      float f0 = exp2_fast((A1R)[base_ + 0]);                                 \
      float f1 = exp2_fast((A1R)[base_ + 1]);                                 \
      float f2 = exp2_fast((A1R)[base_ + 2]);                                 \
      float f3 = exp2_fast((A1R)[base_ + 3]);                                 \
      float f4 = exp2_fast((A1R)[base_ + 4]);                                 \
      float f5 = exp2_fast((A1R)[base_ + 5]);                                 \
      float f6 = exp2_fast((A1R)[base_ + 6]);                                 \
      float f7 = exp2_fast((A1R)[base_ + 7]);                                 \
      floatx2 w0_, w1_;                                                       \
      w0_[0] = f0 + f4; w0_[1] = f1 + f5; pB0 += w0_;                         \
      w1_[0] = f2 + f6; w1_[1] = f3 + f7; pB1 += w1_;                         \
      unsigned A1_ = pk2(f0, f1), B1_ = pk2(f2, f3);                          \
      unsigned C1_ = pk2(f4, f5), D1_ = pk2(f6, f7);                          \
      unsigned px0 = A0_, pz0 = C0_; plane32(px0, pz0);                       \
      unsigned py0 = B0_, pw0 = D0_; plane32(py0, pw0);                       \
      unsigned px1 = A1_, pz1 = C1_; plane32(px1, pz1);                       \
      unsigned py1 = B1_, pw1 = D1_; plane32(py1, pw1);                       \
      union { uint4 u; bf16x8 v; } pf0_, pf1_;                                \
      pf0_.u.x = px0; pf0_.u.y = py0; pf0_.u.z = pz0; pf0_.u.w = pw0;         \
      pf1_.u.x = px1; pf1_.u.y = py1; pf1_.u.z = pz1; pf1_.u.w = pw1;         \
      __builtin_amdgcn_s_setprio(1);                                          \
      _Pragma("unroll")                                                       \
      for (int t2_ = 0; t2_ < 2; t2_++) {                                     \
        bf16x8 vf_ = sl_ ? (VFB)[t2_] : (VFA)[t2_];                           \
        ov[t2_]     = __builtin_amdgcn_mfma_f32_32x32x16_bf16(vf_, pf0_.v, ov[t2_], 0, 0, 0); \
        ov[2 + t2_] = __builtin_amdgcn_mfma_f32_32x32x16_bf16(vf_, pf1_.v, ov[2 + t2_], 0, 0, 0); \
      }                                                                       \
      __builtin_amdgcn_s_setprio(0);                                          \
    }                                                                         \
  } while (0)

__global__ __launch_bounds__(256, 2) void k_attn(const bf16_t* __restrict__ Qb,
                                                 const bf16_t* __restrict__ Kb,
                                                 const bf16_t* __restrict__ VtG,
                                                 const float* __restrict__ mask,
                                                 float* __restrict__ out) {
  __shared__ float smem[10240];  // 40960 B
  bf16_t* lds = (bf16_t*)smem;   // staging: 2 bufs x (K 4096 + V 4096) elems
  float* mlds = smem + 8192;     // m12[k] = mask[k]*log2e - 12, 2048 floats

  int tid = threadIdx.x, wq = tid >> 6, lane = tid & 63;
  int q5 = lane & 31, h5 = lane >> 5;

  int id = blockIdx.x;            // 512 blocks: XCD x owns bh = x*8..x*8+7
  int x = id & 7, w = id >> 3;
  int bh = x * 8 + (w >> 3), qt = w & 7;
  int b = bh >> 4, hh = bh & 15;

  const bf16_t* Qp = Qb + (size_t)bh * 131072;
  const bf16_t* Kp = Kb + (size_t)bh * 131072;
  const bf16_t* Vp = VtG + (size_t)bh * 131072;
  const float* mp = mask + b * 2048;

  // mask -> LDS: m12[k] = mask[k]*log2e - 12 (8 floats per thread)
#pragma unroll
  for (int j = 0; j < 2; j++) {
    float4 mv = *(const float4*)(mp + tid * 8 + j * 4);
    float4 sv;
    sv.x = mv.x * 1.4426950408890f - 12.0f;
    sv.y = mv.y * 1.4426950408890f - 12.0f;
    sv.z = mv.z * 1.4426950408890f - 12.0f;
    sv.w = mv.w * 1.4426950408890f - 12.0f;
    *(float4*)(mlds + tid * 8 + j * 4) = sv;
  }

  int q0 = qt * 256 + wq * 64;
  bf16x8 qf0[4], qf1[4];  // Q as B-operand for the two 32-q n-tiles
#pragma unroll
  for (int s = 0; s < 4; s++) {
    qf0[s] = *(const bf16x8*)(Qp + (size_t)(q0 + q5) * 64 + s * 16 + h5 * 8);
    qf1[s] = *(const bf16x8*)(Qp + (size_t)(q0 + 32 + q5) * 64 + s * 16 + h5 * 8);
  }

  // ext B fragment for the mask tile: B_ext[0][q] = 1, rest 0
  union { uint4 u; bf16x8 v; } qfe;
  qfe.u.x = h5 ? 0u : 0x00003f80u;
  qfe.u.y = 0u; qfe.u.z = 0u; qfe.u.w = 0u;

  // hoisted LDS fragment offsets (same formula for K and Vt tiles)
  int off[2][4];
#pragma unroll
  for (int j = 0; j < 2; j++)
#pragma unroll
    for (int s = 0; s < 4; s++)
      off[j][s] = (j * 32 + q5) * 64 + (((2 * s + h5) ^ (q5 & 7)) * 8);

  // staging: two 8-row chunks per wave per tile (4 waves, 8 chunks each array)
  int r0 = wq * 16 + (lane >> 3);
  int slot = (lane & 7) ^ ((lane >> 3) & 7);
  const bf16_t* kg0 = Kp + (size_t)r0 * 64 + slot * 8;
  const bf16_t* kg1 = kg0 + 512;
  const bf16_t* vg0 = Vp + (size_t)r0 * 2048 + slot * 8;
  const bf16_t* vg1 = vg0 + 16384;
  int c0 = wq * 2;

  // persistent zero accumulator (C operand of the mask-tile MFMAs)
  floatx16 zed;
#pragma unroll
  for (int r = 0; r < 16; r++) zed[r] = 0.f;

  floatx16 ov[4];  // [u*2+t2]: O^T[d = t2*32 + ...][q = q0 + u*32 + q5]
#pragma unroll
  for (int t2 = 0; t2 < 4; t2++)
#pragma unroll
    for (int r = 0; r < 16; r++) ov[t2][r] = 0.f;
  // denominator partials, packed pairs (identical FP order to scalar form)
  floatx2 pA0, pA1, pB0, pB1;
  pA0[0] = pA0[1] = pA1[0] = pA1[1] = 0.f;
  pB0[0] = pB0[1] = pB1[0] = pB1[1] = 0.f;

  // pipeline register sets (A = even halves tt=0, B = odd halves tt=1)
  floatx16 aA0, aA1, aB0, aB1;
  bf16x8 vfaA[2], vfbA[2], vfaB[2], vfbB[2];

  // stage tile 0 into buf 0
  {
    bf16_t* bK = lds;
    bf16_t* bV = lds + 4096;
    glds16(kg0, bK + c0 * 512); glds16(kg1, bK + c0 * 512 + 512);
    glds16(vg0, bV + c0 * 512); glds16(vg1, bV + c0 * 512 + 512);
    kg0 += 4096; kg1 += 4096; vg0 += 64; vg1 += 64;
  }

  // ---- peeled iteration 0: fill the pipeline ----
  {
    __syncthreads();
    {  // prefetch tile 1 into buf 1
      bf16_t* bK = lds + 8192;
      bf16_t* bV = bK + 4096;
      glds16(kg0, bK + c0 * 512); glds16(kg1, bK + c0 * 512 + 512);
      glds16(vg0, bV + c0 * 512); glds16(vg1, bV + c0 * 512 + 512);
      kg0 += 4096; kg1 += 4096; vg0 += 64; vg1 += 64;
    }
    const bf16_t* bK = lds;
    const bf16_t* bV = bK + 4096;

    union { uint4 u; bf16x8 v; } kfe[2];
    kfe[0].u.x = h5 ? 0u : pk2(mlds[q5], 0.f);
    kfe[1].u.x = h5 ? 0u : pk2(mlds[32 + q5], 0.f);
    kfe[0].u.y = 0u; kfe[0].u.z = 0u; kfe[0].u.w = 0u;
    kfe[1].u.y = 0u; kfe[1].u.z = 0u; kfe[1].u.w = 0u;

    QKHALF(0, aA0, aA1, vfaA, vfbA);
    QKHALF(1, aB0, aB1, vfaB, vfbB);
    SMPV(aA0, aA1, vfaA, vfbA);
  }

  for (int it = 1; it < 32; ++it) {
    int kk0 = it * 64, cur = it & 1;
    __syncthreads();
    if (it + 1 < 32) {  // prefetch next tile into other buffer
      bf16_t* bK = lds + (cur ^ 1) * 8192;
      bf16_t* bV = bK + 4096;
      glds16(kg0, bK + c0 * 512); glds16(kg1, bK + c0 * 512 + 512);
      glds16(vg0, bV + c0 * 512); glds16(vg1, bV + c0 * 512 + 512);
      kg0 += 4096; kg1 += 4096; vg0 += 64; vg1 += 64;
    }
    const bf16_t* bK = lds + cur * 8192;
    const bf16_t* bV = bK + 4096;

    // mask fragments for both 32-key halves
    union { uint4 u; bf16x8 v; } kfe[2];
    kfe[0].u.x = h5 ? 0u : pk2(mlds[kk0 + q5], 0.f);
    kfe[1].u.x = h5 ? 0u : pk2(mlds[kk0 + 32 + q5], 0.f);
    kfe[0].u.y = 0u; kfe[0].u.z = 0u; kfe[0].u.w = 0u;
    kfe[1].u.y = 0u; kfe[1].u.z = 0u; kfe[1].u.w = 0u;

    // pipelined: QK(cur half) then SMPV(previous half) — exp reads ready
    // registers while the fresh QK chain drains the MFMA pipe.
    QKHALF(0, aA0, aA1, vfaA, vfbA);
    SMPV(aB0, aB1, vfaB, vfbB);
    QKHALF(1, aB0, aB1, vfaB, vfbB);
    SMPV(aA0, aA1, vfaA, vfbA);
  }
  // drain the pipeline: last odd half
  SMPV(aB0, aB1, vfaB, vfbB);

  // denominators per q-subtile (halves of each lane-pair = disjoint k-sets)
  float ls0 = (pA0[0] + pA0[1]) + (pA1[0] + pA1[1]);
  float ls1 = (pB0[0] + pB0[1]) + (pB1[0] + pB1[1]);
  ls0 += __shfl_xor(ls0, 32);
  ls1 += __shfl_xor(ls1, 32);
  float rl0 = 1.f / ls0, rl1 = 1.f / ls1;

  // epilogue: two half-passes through a 128x68 LDS transpose buffer
  int qbase0 = b * 2048 + qt * 256;
#pragma unroll
  for (int half = 0; half < 2; half++) {
    __syncthreads();
    if ((wq >> 1) == half) {
      int qw = (wq & 1) * 64;  // wave offset within the half
#pragma unroll
      for (int u = 0; u < 2; u++) {
        float rl = u ? rl1 : rl0;
#pragma unroll
        for (int t2 = 0; t2 < 2; t2++)
#pragma unroll
          for (int r = 0; r < 16; r++) {
            int d = t2 * 32 + (r & 3) + 8 * (r >> 2) + 4 * h5;
            smem[(qw + u * 32 + q5) * 68 + d] = ov[u * 2 + t2][r] * rl;
          }
      }
    }
    __syncthreads();
    int qbase = qbase0 + half * 128;
#pragma unroll
    for (int i = 0; i < 8; i++) {
      int slot2 = i * 256 + tid;
      int q = slot2 >> 4, c = slot2 & 15;
      float4 v = *(const float4*)(smem + q * 68 + c * 4);
      *(float4*)(out + (size_t)(qbase + q) * 1024 + hh * 64 + c * 4) = v;
    }
  }
}

// ------------------------------ launcher -----------------------------------
extern "C" void kernel_launch(void* const* d_in, const int* in_sizes, int n_in,
                              void* d_out, int out_size, void* d_ws, size_t ws_size,
                              hipStream_t stream) {
  const float* X    = (const float*)d_in[0];
  const float* mask = (const float*)d_in[1];
  const float* Wq   = (const float*)d_in[2];
  const float* bq   = (const float*)d_in[3];
  const float* Wk   = (const float*)d_in[4];
  const float* bk   = (const float*)d_in[5];
  const float* Wv   = (const float*)d_in[6];
  const float* bv   = (const float*)d_in[7];
  float* out = (float*)d_out;

  char* ws = (char*)d_ws;
  bf16_t* Xb = (bf16_t*)ws;
  bf16_t* Wt = (bf16_t*)(ws + 16777216);
  bf16_t* Qb = (bf16_t*)(ws + 23068672);
  bf16_t* Kb = (bf16_t*)(ws + 39845888);
  bf16_t* Vt = (bf16_t*)(ws + 56623104);

  k_prep<<<11264, 256, 0, stream>>>(X, Xb, Wq, Wk, Wv, Wt);
  k_qkv<<<768, 512, 147456, stream>>>(Xb, Wt, bq, bk, bv, Qb, Kb, Vt);
  k_attn<<<512, 256, 0, stream>>>(Qb, Kb, Vt, mask, out);
}